// Round 8
// baseline (398.378 us; speedup 1.0000x reference)
//
#include <hip/hip_runtime.h>

// ---------- types ----------
typedef __bf16 bf16x8 __attribute__((ext_vector_type(8)));
typedef __bf16 bf16x4 __attribute__((ext_vector_type(4)));
typedef float  f32x4  __attribute__((ext_vector_type(4)));

// =====================================================================
// ALGEBRAIC REWRITE:
//   S = Q Kp^T = T (Wq^T Wk) E^T = QW E^T        (QW = T WW1, WW1 = Wq^T Wk)
//   F = (A E Wv^T) Wo^T = (A E) (Wo Wv)^T = U WW2^T
// -> no K/V projections, no 67 MB intermediates. E read twice (2nd L2-hot).
// =====================================================================

// =====================================================================
// prep_w: blocks 0..63:  WW1[m][k] = sum_d Wq[d][m] Wk[d][k]   (8 m/block)
//         blocks 64..127: WW2t[d][m] = sum_dd Wv[dd][d] Wo[m][dd] (8 d/block)
// =====================================================================
__global__ __launch_bounds__(256) void prep_w(const float* __restrict__ Wq,
                                              const float* __restrict__ Wk,
                                              const float* __restrict__ Wo,
                                              const float* __restrict__ Wv,
                                              float* __restrict__ WW1,
                                              float* __restrict__ WW2t) {
  __shared__ float sA[8][256];
  __shared__ float sB[512][9];   // padded stride 9 -> conflict-free
  const int t = threadIdx.x;
  const int bid = blockIdx.x;
  if (bid < 64) {
    const int m0 = bid * 8;
    f32x4 a0 = *(const f32x4*)(Wq + (size_t)t * 512 + m0);
    f32x4 a1 = *(const f32x4*)(Wq + (size_t)t * 512 + m0 + 4);
#pragma unroll
    for (int j = 0; j < 4; ++j) { sA[j][t] = a0[j]; sA[4 + j][t] = a1[j]; }
    __syncthreads();
    float acc[8] = {}, acc2[8] = {};
    for (int d = 0; d < 256; ++d) {
      const float w1 = Wk[(size_t)d * 512 + t];
      const float w2 = Wk[(size_t)d * 512 + t + 256];
#pragma unroll
      for (int j = 0; j < 8; ++j) {
        const float qv = sA[j][d];
        acc[j] += qv * w1; acc2[j] += qv * w2;
      }
    }
#pragma unroll
    for (int j = 0; j < 8; ++j) {
      WW1[(size_t)(m0 + j) * 512 + t] = acc[j];
      WW1[(size_t)(m0 + j) * 512 + t + 256] = acc2[j];
    }
  } else {
    const int d0 = (bid - 64) * 8;
    f32x4 a0 = *(const f32x4*)(Wv + (size_t)t * 512 + d0);
    f32x4 a1 = *(const f32x4*)(Wv + (size_t)t * 512 + d0 + 4);
#pragma unroll
    for (int j = 0; j < 4; ++j) { sA[j][t] = a0[j]; sA[4 + j][t] = a1[j]; }
    float acc[8] = {}, acc2[8] = {};
    for (int g = 0; g < 32; ++g) {
      __syncthreads();
      f32x4 b0 = *(const f32x4*)(Wo + (size_t)t * 256 + g * 8);
      f32x4 b1 = *(const f32x4*)(Wo + (size_t)t * 256 + g * 8 + 4);
      f32x4 c0 = *(const f32x4*)(Wo + (size_t)(t + 256) * 256 + g * 8);
      f32x4 c1 = *(const f32x4*)(Wo + (size_t)(t + 256) * 256 + g * 8 + 4);
#pragma unroll
      for (int j = 0; j < 4; ++j) {
        sB[t][j] = b0[j]; sB[t][4 + j] = b1[j];
        sB[t + 256][j] = c0[j]; sB[t + 256][4 + j] = c1[j];
      }
      __syncthreads();
#pragma unroll
      for (int dd = 0; dd < 8; ++dd) {
        const float w1 = sB[t][dd], w2 = sB[t + 256][dd];
#pragma unroll
        for (int j = 0; j < 8; ++j) {
          const float v = sA[j][g * 8 + dd];
          acc[j] += v * w1; acc2[j] += v * w2;
        }
      }
    }
#pragma unroll
    for (int j = 0; j < 8; ++j) {
      WW2t[(size_t)(d0 + j) * 512 + t] = acc[j];
      WW2t[(size_t)(d0 + j) * 512 + t + 256] = acc2[j];
    }
  }
}

// =====================================================================
// prep_qw: QW[r][k] = sum_m T[r][m] WW1[m][k], bf16 out. 8 r/block.
// =====================================================================
__global__ __launch_bounds__(256) void prep_qw(const float* __restrict__ T,
                                               const float* __restrict__ WW1,
                                               __bf16* __restrict__ QW) {
  __shared__ float Tl[8][512];
  const int t = threadIdx.x;
  const int r0 = blockIdx.x * 8;
#pragma unroll
  for (int s = 0; s < 4; ++s) {
    const int ch = t + s * 256;
    const int j = ch >> 7, m4 = (ch & 127) * 4;
    f32x4 v = *(const f32x4*)(T + (size_t)(r0 + j) * 512 + m4);
    *(f32x4*)&Tl[j][m4] = v;
  }
  __syncthreads();
  float acc[8] = {}, acc2[8] = {};
  for (int m = 0; m < 512; ++m) {
    const float w1 = WW1[(size_t)m * 512 + t];
    const float w2 = WW1[(size_t)m * 512 + t + 256];
#pragma unroll
    for (int j = 0; j < 8; ++j) {
      const float tv = Tl[j][m];
      acc[j] += tv * w1; acc2[j] += tv * w2;
    }
  }
#pragma unroll
  for (int j = 0; j < 8; ++j) {
    QW[(size_t)(r0 + j) * 512 + t] = (__bf16)acc[j];
    QW[(size_t)(r0 + j) * 512 + t + 256] = (__bf16)acc2[j];
  }
}

// =====================================================================
// attn3: grid (16 xb, 16 b). Block covers 256 n in 8 chunks of 32.
// Per chunk: S[32i x 32n] = QW E^T via MFMA (E B-frags straight from
// global f32 + cvt); P = exp(S/16 + logP) (no max pass — scores tiny,
// logP in [-2.3,-0.105]); P -> Pws(bf16) + Plds; barrier;
// U[32i x 512m] += P E via MFMA (E read column-wise, 64B-coalesced
// scalar loads, L2-hot from S pass). LDS = 2.6 KB. acc in AGPRs.
// =====================================================================
__global__ __launch_bounds__(256, 3) void attn3(const float* __restrict__ E,
                                                const __bf16* __restrict__ QW,
                                                const float* __restrict__ Pb,
                                                __bf16* __restrict__ Pws,
                                                float* __restrict__ Upart,
                                                float* __restrict__ rowsum) {
  __shared__ __bf16 Plds[32][40];   // pad 40 -> <=2-way banks
  const int tid = threadIdx.x, lane = tid & 63, w = tid >> 6;
  const int q = lane >> 4, ln = lane & 15;
  const int hi = w >> 1, hn = w & 1;   // wave = (i-half, n-half/m-half)
  const int xb = blockIdx.x, b = blockIdx.y;

  f32x4 accU[16] = {};
  float rs[4] = {};
  const __bf16* QWrow = QW + (size_t)(b * 32 + hi * 16 + ln) * 512;

  for (int c = 0; c < 8; ++c) {
    const int n0c = xb * 256 + c * 32;
    // ---- S: A=QW[i][k], B=E[n][k], k=512 ----
    f32x4 accS = {};
    const float* Erow = E + (size_t)(b * 4096 + n0c + hn * 16 + ln) * 512;
#pragma unroll 4
    for (int kk = 0; kk < 16; ++kk) {
      bf16x8 a = *(const bf16x8*)(QWrow + kk * 32 + q * 8);
      f32x4 e0 = *(const f32x4*)(Erow + kk * 32 + q * 8);
      f32x4 e1 = *(const f32x4*)(Erow + kk * 32 + q * 8 + 4);
      bf16x8 bb;
      bb[0] = (__bf16)e0[0]; bb[1] = (__bf16)e0[1];
      bb[2] = (__bf16)e0[2]; bb[3] = (__bf16)e0[3];
      bb[4] = (__bf16)e1[0]; bb[5] = (__bf16)e1[1];
      bb[6] = (__bf16)e1[2]; bb[7] = (__bf16)e1[3];
      accS = __builtin_amdgcn_mfma_f32_16x16x32_bf16(a, bb, accS, 0, 0, 0);
    }
    // ---- P = exp(S*SCALE + logP) ----
    float p = Pb[b * 4096 + n0c + hn * 16 + ln];
    p = fminf(fmaxf(p, 0.1f), 0.9f);
    const float lp = __logf(p);
#pragma unroll
    for (int r = 0; r < 4; ++r) {
      const float pv = __expf(accS[r] * 0.0625f + lp);
      const int i = hi * 16 + q * 4 + r;
      rs[r] += pv;
      const __bf16 pbv = (__bf16)pv;
      Pws[(size_t)(b * 32 + i) * 4096 + n0c + hn * 16 + ln] = pbv;
      Plds[i][hn * 16 + ln] = pbv;
    }
    __syncthreads();
    // ---- U: A=P[i][k=n 32], B[m][k=n]=E[n][m] (column loads) ----
    bf16x8 pa = *(const bf16x8*)&Plds[hi * 16 + ln][q * 8];
    const float* ebase = E + (size_t)(b * 4096 + n0c + q * 8) * 512 + hn * 256 + ln;
#pragma unroll
    for (int fd = 0; fd < 16; ++fd) {
      bf16x8 yb;
#pragma unroll
      for (int j = 0; j < 8; ++j)
        yb[j] = (__bf16)ebase[(size_t)j * 512 + fd * 16];
      accU[fd] = __builtin_amdgcn_mfma_f32_16x16x32_bf16(pa, yb, accU[fd], 0, 0, 0);
    }
    __syncthreads();
  }
  // ---- store U partial plane (xb), coalesced f32 ----
  float* Up = Upart + ((size_t)xb * 512 + b * 32) * 512;
#pragma unroll
  for (int fd = 0; fd < 16; ++fd)
#pragma unroll
    for (int r = 0; r < 4; ++r) {
      const int i = hi * 16 + q * 4 + r;
      const int m = hn * 256 + fd * 16 + ln;
      Up[(size_t)i * 512 + m] = accU[fd][r];
    }
  // ---- rowsum partials ----
#pragma unroll
  for (int mm = 1; mm < 16; mm <<= 1)
#pragma unroll
    for (int r = 0; r < 4; ++r) rs[r] += __shfl_xor(rs[r], mm, 64);
  if (ln == 0)
#pragma unroll
    for (int r = 0; r < 4; ++r)
      atomicAdd(&rowsum[b * 32 + hi * 16 + q * 4 + r], rs[r]);
}

// =====================================================================
// norm_p: A(f32) = Pws(bf16) / rowsum[row].
// =====================================================================
__global__ __launch_bounds__(256) void norm_p(const __bf16* __restrict__ Pws,
                                              const float* __restrict__ rowsum,
                                              float* __restrict__ Aout) {
  const size_t idx = ((size_t)blockIdx.x * 256 + threadIdx.x) * 4;
  const int row = (int)(idx >> 12);
  const float invs = 1.0f / rowsum[row];
  bf16x4 p = *(const bf16x4*)(Pws + idx);
  f32x4 o;
  o[0] = (float)p[0] * invs; o[1] = (float)p[1] * invs;
  o[2] = (float)p[2] * invs; o[3] = (float)p[3] * invs;
  *(f32x4*)(Aout + idx) = o;
}

// =====================================================================
// final2: U = sum_xb Upart; G = U @ WW2t (f32 VALU);
// F = G / (||G|| + 1e-8)  (rowsum cancels in L2 norm). 8 rows/block.
// =====================================================================
__global__ __launch_bounds__(256) void final2(const float* __restrict__ Upart,
                                              const float* __restrict__ WW2t,
                                              float* __restrict__ Fout) {
  __shared__ float Ur[8][512];
  __shared__ float sred[4][8];
  __shared__ float ssc[8];
  const int t = threadIdx.x;
  const int r0 = blockIdx.x * 8;
#pragma unroll
  for (int rep = 0; rep < 16; ++rep) {
    const int idx = rep * 256 + t;
    const int j = idx >> 9, m = idx & 511;
    float s = 0.f;
#pragma unroll
    for (int xb = 0; xb < 16; ++xb)
      s += Upart[((size_t)xb * 512 + r0 + j) * 512 + m];
    Ur[j][m] = s;
  }
  __syncthreads();
  float acc[8] = {}, acc2[8] = {};
  for (int d = 0; d < 512; ++d) {
    const float w1 = WW2t[(size_t)d * 512 + t];
    const float w2 = WW2t[(size_t)d * 512 + t + 256];
#pragma unroll
    for (int j = 0; j < 8; ++j) {
      const float u = Ur[j][d];
      acc[j] += u * w1; acc2[j] += u * w2;
    }
  }
  float ps[8];
#pragma unroll
  for (int j = 0; j < 8; ++j) ps[j] = acc[j] * acc[j] + acc2[j] * acc2[j];
#pragma unroll
  for (int mm = 1; mm < 64; mm <<= 1)
#pragma unroll
    for (int j = 0; j < 8; ++j) ps[j] += __shfl_xor(ps[j], mm, 64);
  if ((t & 63) == 0)
#pragma unroll
    for (int j = 0; j < 8; ++j) sred[t >> 6][j] = ps[j];
  __syncthreads();
  if (t < 8) {
    const float tot = sred[0][t] + sred[1][t] + sred[2][t] + sred[3][t];
    ssc[t] = 1.0f / (sqrtf(tot) + 1e-8f);
  }
  __syncthreads();
#pragma unroll
  for (int j = 0; j < 8; ++j) {
    Fout[(size_t)(r0 + j) * 512 + t] = acc[j] * ssc[j];
    Fout[(size_t)(r0 + j) * 512 + t + 256] = acc2[j] * ssc[j];
  }
}

// =====================================================================
extern "C" void kernel_launch(void* const* d_in, const int* in_sizes, int n_in,
                              void* d_out, int out_size, void* d_ws, size_t ws_size,
                              hipStream_t stream) {
  const float* E  = (const float*)d_in[0];  // [16,4096,512]
  const float* T  = (const float*)d_in[1];  // [16,32,512]
  const float* Pb = (const float*)d_in[2];  // [16,4096]
  const float* Wq = (const float*)d_in[3];  // [256,512]
  const float* Wk = (const float*)d_in[4];  // [256,512]
  const float* Wv = (const float*)d_in[5];  // [256,512]
  const float* Wo = (const float*)d_in[6];  // [512,256]

  float* out  = (float*)d_out;
  float* Fout = out;             // [512][512] f32
  float* Aout = out + 262144;    // [512][4096] f32

  char* ws = (char*)d_ws;
  float*  WW1    = (float*)ws;                   // [512][512] f32   1048576 B
  float*  WW2t   = (float*)(ws + 1048576);       // [512][512] f32   1048576 B
  __bf16* QW     = (__bf16*)(ws + 2097152);      // [512][512] bf16   524288 B
  __bf16* Pws    = (__bf16*)(ws + 2621440);      // [512][4096] bf16 4194304 B
  float*  Upart  = (float*)(ws + 6815744);       // [16][512][512]  16777216 B
  float*  rowsum = (float*)(ws + 23592960);      // [512] f32 (2048 B)

  hipMemsetAsync(rowsum, 0, 2048, stream);

  prep_w<<<128, 256, 0, stream>>>(Wq, Wk, Wo, Wv, WW1, WW2t);
  prep_qw<<<64, 256, 0, stream>>>(T, WW1, QW);
  attn3<<<dim3(16, 16), 256, 0, stream>>>(E, QW, Pb, Pws, Upart, rowsum);
  norm_p<<<2048, 256, 0, stream>>>(Pws, rowsum, Aout);
  final2<<<64, 256, 0, stream>>>(Upart, WW2t, Fout);
}